// Round 1
// baseline (116.335 us; speedup 1.0000x reference)
//
#include <hip/hip_runtime.h>
#include <math.h>

// Problem constants: B=64, L=256, H=64
#define PB 64
#define PL 256
#define PH 64
#define TEMP 0.07f
#define NEG_INF_F (-1e9f)

#define KSTRIDE 72            // bf16 elements per staged K row (64 + 8 pad; 144 B, 16B-aligned)
#define KROWB   (KSTRIDE * 2) // 144 bytes per row
#define KSLAB   (PL * KSTRIDE)// elems per c slab (full 256 rows reserved)

typedef short short8 __attribute__((ext_vector_type(8)));   // 8 bf16 bit-patterns
typedef float f32x4 __attribute__((ext_vector_type(4)));

__device__ __forceinline__ unsigned short f32_to_bf16(float f) {
    unsigned int u = __float_as_uint(f);
    u += 0x7FFFu + ((u >> 16) & 1u);    // round to nearest even
    return (unsigned short)(u >> 16);
}

// ---------------- prep: Q bf16 convert + K compact/convert/pad ----------------
// blocks 0..63   : compact K for c=blockIdx.x  (valid kmask rows only, padded stride,
//                  tail zero-rows up to multiple of 16), write nvK[c]
// blocks 64..127 : convert Q for b=blockIdx.x-64
__global__ __launch_bounds__(256)
void prep_kernel(const float* __restrict__ Q,
                 const float* __restrict__ K,
                 const int*   __restrict__ kmask,
                 unsigned short* __restrict__ Qb,
                 unsigned short* __restrict__ Kcomp,
                 int* __restrict__ nvK) {
    const int tid = threadIdx.x;

    if (blockIdx.x >= PB) {
        // ---- Q convert: 16384 elems -> 4096 float4 per b ----
        const int b = blockIdx.x - PB;
        const float4* src = (const float4*)(Q + (size_t)b * PL * PH);
        unsigned short* dst = Qb + (size_t)b * PL * PH;
        #pragma unroll
        for (int it = 0; it < (PL * PH / 4) / 256; ++it) {   // 16 iters
            int i = it * 256 + tid;
            float4 v = src[i];
            ushort4 o;
            o.x = f32_to_bf16(v.x); o.y = f32_to_bf16(v.y);
            o.z = f32_to_bf16(v.z); o.w = f32_to_bf16(v.w);
            *(ushort4*)(dst + (size_t)i * 4) = o;
        }
        return;
    }

    // ---- K compaction for c ----
    const int c    = blockIdx.x;
    const int lane = tid & 63;
    const int wave = tid >> 6;
    __shared__ int posArr[PL];
    __shared__ int wcnt[4];

    const int km = kmask[c * PL + tid];
    unsigned long long bal = __ballot(km != 0);
    int within = __popcll(bal & ((1ull << lane) - 1ull));
    if (lane == 0) wcnt[wave] = __popcll(bal);
    __syncthreads();
    int base = 0;
    #pragma unroll
    for (int w = 0; w < 4; ++w) base += (w < wave) ? wcnt[w] : 0;
    posArr[tid] = km ? (base + within) : -1;
    const int nv = wcnt[0] + wcnt[1] + wcnt[2] + wcnt[3];
    __syncthreads();

    unsigned short* slab = Kcomp + (size_t)c * KSLAB;
    // cooperative compact-copy: wave w handles rows w, w+4, ... (coalesced 256B reads)
    for (int r = wave; r < PL; r += 4) {
        int p = posArr[r];
        if (p >= 0) {
            float v = K[((size_t)c * PL + r) * PH + lane];
            slab[(size_t)p * KSTRIDE + lane] = f32_to_bf16(v);
        }
    }
    // zero-fill tail pad rows (first 64 cols only; pad cols 64..71 are never read as fragments)
    const int rows16 = (nv + 15) & ~15;
    for (int p = nv + wave; p < rows16; p += 4) {
        slab[(size_t)p * KSTRIDE + lane] = 0;
    }
    if (tid == 0) nvK[c] = nv;
}

// ---------------- main scores kernel: one block per (b,c) ----------------
__global__ __launch_bounds__(256)
void colbert_scores_mfma(const unsigned short* __restrict__ Qb,
                         const unsigned short* __restrict__ Kcomp,
                         const int*   __restrict__ nvK,
                         const int*   __restrict__ qmask,
                         float*       __restrict__ scores) {
    const int c = blockIdx.x;
    const int b = blockIdx.y;
    const int tid  = threadIdx.x;
    const int wave = tid >> 6;
    const int lane = tid & 63;
    const int n    = lane & 15;        // col / row-within-tile index
    const int g    = (lane >> 4) & 3;  // quad index

    __shared__ __align__(16) unsigned short Ks[PL * KSTRIDE];  // 36 KB
    __shared__ float qmF[PL];
    __shared__ float red[4];

    const int nv     = nvK[c];
    const int rows16 = (nv + 15) & ~15;
    const int nbytes = rows16 * KROWB;

    qmF[tid] = (float)qmask[b * PL + tid];

    // Stage compacted K via async global->LDS (linear, padded layout identical on both sides).
    // Whole-4KB chunks; over-copy stays within the 36864B slab / LDS buffer, never read.
    {
        const char* gsrc  = (const char*)(Kcomp + (size_t)c * KSLAB);
        char*       lbase = (char*)Ks;
        const int nchunks = (nbytes + 4095) >> 12;
        for (int it = 0; it < nchunks; ++it) {
            int off = it * 4096 + tid * 16;
            __builtin_amdgcn_global_load_lds(
                (const __attribute__((address_space(1))) unsigned int*)(gsrc + off),
                (__attribute__((address_space(3)))       unsigned int*)(lbase + off),
                16, 0, 0);
        }
    }

    // A-fragments (Q) straight from global into registers.
    // Wave handles q rows [wave*64, wave*64+64). lane holds A[m=lane&15][k=g*8+j].
    const int qw0 = wave * 64;
    short8 afrag[4][2];
    {
        const unsigned short* Qrow = Qb + ((size_t)b * PL) * PH;
        #pragma unroll
        for (int rt = 0; rt < 4; ++rt) {
            const unsigned short* p = Qrow + (size_t)(qw0 + rt * 16 + n) * PH + g * 8;
            afrag[rt][0] = *(const short8*)(p);
            afrag[rt][1] = *(const short8*)(p + 32);
        }
    }

    __syncthreads();   // staging + masks visible (syncthreads drains vmcnt/lgkmcnt)

    float maxv[4][4];
    #pragma unroll
    for (int rt = 0; rt < 4; ++rt)
        #pragma unroll
        for (int r = 0; r < 4; ++r) maxv[rt][r] = NEG_INF_F;

    const f32x4 ZERO4 = (f32x4){0.f, 0.f, 0.f, 0.f};
    const int ntFull   = nv >> 4;
    const int tailCols = nv & 15;
    const unsigned short* krow0 = &Ks[n * KSTRIDE + g * 8];

    // main loop: pairs of full 16-col tiles; no masking needed (all columns valid)
    int ct = 0;
    for (; ct + 1 < ntFull; ct += 2) {
        const unsigned short* ka = krow0 + ct * 16 * KSTRIDE;
        short8 kA0 = *(const short8*)(ka);
        short8 kA1 = *(const short8*)(ka + 32);
        short8 kB0 = *(const short8*)(ka + 16 * KSTRIDE);
        short8 kB1 = *(const short8*)(ka + 16 * KSTRIDE + 32);

        f32x4 accA[4], accB[4];
        #pragma unroll
        for (int rt = 0; rt < 4; ++rt) {
            accA[rt] = __builtin_amdgcn_mfma_f32_16x16x32_bf16(afrag[rt][0], kA0, ZERO4, 0, 0, 0);
            accB[rt] = __builtin_amdgcn_mfma_f32_16x16x32_bf16(afrag[rt][0], kB0, ZERO4, 0, 0, 0);
        }
        #pragma unroll
        for (int rt = 0; rt < 4; ++rt) {
            accA[rt] = __builtin_amdgcn_mfma_f32_16x16x32_bf16(afrag[rt][1], kA1, accA[rt], 0, 0, 0);
            accB[rt] = __builtin_amdgcn_mfma_f32_16x16x32_bf16(afrag[rt][1], kB1, accB[rt], 0, 0, 0);
        }
        // running max; nested fmax -> v_max3_f32
        #pragma unroll
        for (int rt = 0; rt < 4; ++rt)
            #pragma unroll
            for (int r = 0; r < 4; ++r)
                maxv[rt][r] = fmaxf(maxv[rt][r], fmaxf(accA[rt][r], accB[rt][r]));
    }

    // leftover single full tile
    if (ntFull & 1) {
        const unsigned short* ka = krow0 + ct * 16 * KSTRIDE;
        short8 k0 = *(const short8*)(ka);
        short8 k1 = *(const short8*)(ka + 32);
        f32x4 acc[4];
        #pragma unroll
        for (int rt = 0; rt < 4; ++rt)
            acc[rt] = __builtin_amdgcn_mfma_f32_16x16x32_bf16(afrag[rt][0], k0, ZERO4, 0, 0, 0);
        #pragma unroll
        for (int rt = 0; rt < 4; ++rt)
            acc[rt] = __builtin_amdgcn_mfma_f32_16x16x32_bf16(afrag[rt][1], k1, acc[rt], 0, 0, 0);
        #pragma unroll
        for (int rt = 0; rt < 4; ++rt)
            #pragma unroll
            for (int r = 0; r < 4; ++r)
                maxv[rt][r] = fmaxf(maxv[rt][r], acc[rt][r]);
        ct++;
    }

    // tail tile: pad lanes get NEG_INF via the MFMA C-operand bias (no per-element cndmask)
    if (tailCols) {
        float biasv = (n < tailCols) ? 0.0f : NEG_INF_F;
        f32x4 BIAS4 = (f32x4){biasv, biasv, biasv, biasv};
        const unsigned short* ka = krow0 + ct * 16 * KSTRIDE;
        short8 k0 = *(const short8*)(ka);
        short8 k1 = *(const short8*)(ka + 32);
        f32x4 acc[4];
        #pragma unroll
        for (int rt = 0; rt < 4; ++rt)
            acc[rt] = __builtin_amdgcn_mfma_f32_16x16x32_bf16(afrag[rt][0], k0, BIAS4, 0, 0, 0);
        #pragma unroll
        for (int rt = 0; rt < 4; ++rt)
            acc[rt] = __builtin_amdgcn_mfma_f32_16x16x32_bf16(afrag[rt][1], k1, acc[rt], 0, 0, 0);
        #pragma unroll
        for (int rt = 0; rt < 4; ++rt)
            #pragma unroll
            for (int r = 0; r < 4; ++r)
                maxv[rt][r] = fmaxf(maxv[rt][r], acc[rt][r]);
    }

    // Max across the 16 lanes (cols) of each quad group.
    #pragma unroll
    for (int rt = 0; rt < 4; ++rt)
        #pragma unroll
        for (int r = 0; r < 4; ++r) {
            float mv = maxv[rt][r];
            mv = fmaxf(mv, __shfl_xor(mv, 1, 16));
            mv = fmaxf(mv, __shfl_xor(mv, 2, 16));
            mv = fmaxf(mv, __shfl_xor(mv, 4, 16));
            mv = fmaxf(mv, __shfl_xor(mv, 8, 16));
            maxv[rt][r] = mv;
        }

    // qmask-weighted sum; count each row once (n==0 lanes).
    float partial = 0.0f;
    if (n == 0) {
        #pragma unroll
        for (int rt = 0; rt < 4; ++rt)
            #pragma unroll
            for (int r = 0; r < 4; ++r) {
                int row = qw0 + rt * 16 + g * 4 + r;
                partial += maxv[rt][r] * qmF[row];
            }
    }
    partial += __shfl_xor(partial, 16, 64);
    partial += __shfl_xor(partial, 32, 64);
    if (lane == 0) red[wave] = partial;
    __syncthreads();
    if (tid == 0) {
        float total = red[0] + red[1] + red[2] + red[3];
        scores[b * PB + c] = total * (1.0f / TEMP);
    }
}

// ---------------- finalize: log-softmax CE ----------------
__global__ void finalize_kernel(const float* __restrict__ scores,
                                const int*   __restrict__ labels,
                                float*       __restrict__ out) {
    const int r = threadIdx.x;   // 64 threads, one per row
    const float* row = scores + r * PB;
    float mx = NEG_INF_F;
    for (int j = 0; j < PB; ++j) mx = fmaxf(mx, row[j]);
    float se = 0.0f;
    for (int j = 0; j < PB; ++j) se += expf(row[j] - mx);
    float logp_diag = row[r] - mx - logf(se);
    float w = (float)labels[r];
    float wd = w * logp_diag;
    #pragma unroll
    for (int off = 32; off >= 1; off >>= 1) {
        wd += __shfl_xor(wd, off, 64);
        w  += __shfl_xor(w,  off, 64);
    }
    if (r == 0) out[0] = -wd / fmaxf(w, 1.0f);
}

extern "C" void kernel_launch(void* const* d_in, const int* in_sizes, int n_in,
                              void* d_out, int out_size, void* d_ws, size_t ws_size,
                              hipStream_t stream) {
    const float* Q      = (const float*)d_in[0];
    const float* K      = (const float*)d_in[1];
    const int*   labels = (const int*)d_in[2];
    const int*   qmask  = (const int*)d_in[3];
    const int*   kmask  = (const int*)d_in[4];
    float*       out    = (float*)d_out;

    // ws layout: [scores 16KB][Qb 2MB][Kcomp 2.25MB][nvK 256B]
    char* ws = (char*)d_ws;
    float*          scores = (float*)ws;
    unsigned short* Qb     = (unsigned short*)(ws + 16 * 1024);
    unsigned short* Kcomp  = (unsigned short*)(ws + 16 * 1024 + 2 * 1024 * 1024);
    int*            nvK    = (int*)(ws + 16 * 1024 + 2 * 1024 * 1024 + (size_t)PB * KSLAB * 2);

    prep_kernel<<<128, 256, 0, stream>>>(Q, K, kmask, Qb, Kcomp, nvK);

    dim3 grid(PB, PB);
    colbert_scores_mfma<<<grid, 256, 0, stream>>>(Qb, Kcomp, nvK, qmask, scores);
    finalize_kernel<<<1, 64, 0, stream>>>(scores, labels, out);
}

// Round 3
// 103.677 us; speedup vs baseline: 1.1221x; 1.1221x over previous
//
#include <hip/hip_runtime.h>
#include <math.h>

// Problem constants: B=64, L=256, H=64
#define PB 64
#define PL 256
#define PH 64
#define TEMP 0.07f
#define NEG_INF_F (-1e9f)

#define KSTRIDE 72            // bf16 elements per staged K row (64 + 8 pad; 144 B, 16B-aligned)
#define KROWB   (KSTRIDE * 2) // 144 bytes per row
#define KSLAB   (PL * KSTRIDE)// elems per c slab (full 256 rows reserved)

typedef short short8 __attribute__((ext_vector_type(8)));   // 8 bf16 bit-patterns
typedef float f32x4 __attribute__((ext_vector_type(4)));

__device__ __forceinline__ unsigned short f32_to_bf16(float f) {
    unsigned int u = __float_as_uint(f);
    u += 0x7FFFu + ((u >> 16) & 1u);    // round to nearest even
    return (unsigned short)(u >> 16);
}

// ---------------- prep: Q bf16 convert + K compact/convert/pad ----------------
// blocks 0..255   : K compaction. c = bid>>2, quarter = bid&3 (rows q*64 .. q*64+63).
//                   All 4 quarter-blocks redundantly compute the (cheap) position scan,
//                   then copy their 64 rows with 16 lanes per row (float4 in, ushort4 out).
// blocks 256..511 : Q convert. b = (bid-256)>>2, quarter = (bid-256)&3;
//                   each block converts 1024 float4 (quarter of one b-slab).
__global__ __launch_bounds__(256)
void prep_kernel(const float* __restrict__ Q,
                 const float* __restrict__ K,
                 const int*   __restrict__ kmask,
                 unsigned short* __restrict__ Qb,
                 unsigned short* __restrict__ Kcomp,
                 int* __restrict__ nvK) {
    const int tid = threadIdx.x;

    if (blockIdx.x >= 256) {
        // ---- Q convert ----
        const int bb      = blockIdx.x - 256;
        const int b       = bb >> 2;
        const int quarter = bb & 3;
        const float4* src = (const float4*)(Q + (size_t)b * PL * PH) + quarter * 1024;
        unsigned short* dst = Qb + (size_t)b * PL * PH + quarter * 4096;
        #pragma unroll
        for (int it = 0; it < 4; ++it) {
            int i = it * 256 + tid;
            float4 v = src[i];
            ushort4 o;
            o.x = f32_to_bf16(v.x); o.y = f32_to_bf16(v.y);
            o.z = f32_to_bf16(v.z); o.w = f32_to_bf16(v.w);
            *(ushort4*)(dst + (size_t)i * 4) = o;
        }
        return;
    }

    // ---- K compaction ----
    const int c       = blockIdx.x >> 2;
    const int quarter = blockIdx.x & 3;
    const int lane = tid & 63;
    const int wave = tid >> 6;
    __shared__ int posArr[PL];
    __shared__ int wcnt[4];

    const int km = kmask[c * PL + tid];
    unsigned long long bal = __ballot(km != 0);
    int within = __popcll(bal & ((1ull << lane) - 1ull));
    if (lane == 0) wcnt[wave] = __popcll(bal);
    __syncthreads();
    int base = 0;
    #pragma unroll
    for (int w = 0; w < 4; ++w) base += (w < wave) ? wcnt[w] : 0;
    posArr[tid] = km ? (base + within) : -1;
    const int nv = wcnt[0] + wcnt[1] + wcnt[2] + wcnt[3];
    __syncthreads();

    unsigned short* slab = Kcomp + (size_t)c * KSLAB;
    const int sub = lane >> 4;     // row-within-group 0..3
    const int cl  = lane & 15;     // 16B column chunk

    // copy 64 rows: 4 waves x 4 rows/iter x 4 iters; 16 lanes per row.
    #pragma unroll
    for (int it = 0; it < 4; ++it) {
        int r = quarter * 64 + it * 16 + wave * 4 + sub;
        int p = posArr[r];
        if (p >= 0) {
            float4 v = *(const float4*)(K + ((size_t)c * PL + r) * PH + cl * 4);
            ushort4 o;
            o.x = f32_to_bf16(v.x); o.y = f32_to_bf16(v.y);
            o.z = f32_to_bf16(v.z); o.w = f32_to_bf16(v.w);
            *(ushort4*)(slab + (size_t)p * KSTRIDE + cl * 4) = o;
        }
    }

    // zero-fill tail pad rows up to multiple of 16 (only the owning quarter writes)
    const int rows16 = (nv + 15) & ~15;
    const int padChunks = (rows16 - nv) * 16;   // ushort4 chunks, <= 240
    if (tid < padChunks) {
        int row = nv + (tid >> 4);
        if (row >= quarter * 64 && row < quarter * 64 + 64) {
            *(ushort4*)(slab + (size_t)row * KSTRIDE + (tid & 15) * 4) = (ushort4){0, 0, 0, 0};
        }
    }
    if (quarter == 0 && tid == 0) nvK[c] = nv;
}

// ---------------- main scores kernel: one block per (b,c) ----------------
__global__ __launch_bounds__(256)
void colbert_scores_mfma(const unsigned short* __restrict__ Qb,
                         const unsigned short* __restrict__ Kcomp,
                         const int*   __restrict__ nvK,
                         const int*   __restrict__ qmask,
                         float*       __restrict__ scores) {
    const int c = blockIdx.x;
    const int b = blockIdx.y;
    const int tid  = threadIdx.x;
    const int wave = tid >> 6;
    const int lane = tid & 63;
    const int n    = lane & 15;        // col / row-within-tile index
    const int g    = (lane >> 4) & 3;  // quad index

    __shared__ __align__(16) unsigned short Ks[PL * KSTRIDE];  // 36 KB
    __shared__ float red[4];

    const int nv     = nvK[c];
    const int rows16 = (nv + 15) & ~15;
    const int nbytes = rows16 * KROWB;

    // Stage compacted K via async global->LDS (linear, padded layout identical on both sides).
    // Whole-4KB chunks; over-copy stays within the 36864B slab / LDS buffer, never read.
    {
        const char* gsrc  = (const char*)(Kcomp + (size_t)c * KSLAB);
        char*       lbase = (char*)Ks;
        const int nchunks = (nbytes + 4095) >> 12;
        for (int it = 0; it < nchunks; ++it) {
            int off = it * 4096 + tid * 16;
            __builtin_amdgcn_global_load_lds(
                (const __attribute__((address_space(1))) unsigned int*)(gsrc + off),
                (__attribute__((address_space(3)))       unsigned int*)(lbase + off),
                16, 0, 0);
        }
    }

    // A-fragments (Q) straight from global into registers.
    // Wave handles q rows [wave*64, wave*64+64). lane holds A[m=lane&15][k=g*8+j].
    const int qw0 = wave * 64;
    short8 afrag[4][2];
    {
        const unsigned short* Qrow = Qb + ((size_t)b * PL) * PH;
        #pragma unroll
        for (int rt = 0; rt < 4; ++rt) {
            const unsigned short* p = Qrow + (size_t)(qw0 + rt * 16 + n) * PH + g * 8;
            afrag[rt][0] = *(const short8*)(p);
            afrag[rt][1] = *(const short8*)(p + 32);
        }
    }

    __syncthreads();   // staging visible (syncthreads drains vmcnt/lgkmcnt)

    float maxv[4][4];
    #pragma unroll
    for (int rt = 0; rt < 4; ++rt)
        #pragma unroll
        for (int r = 0; r < 4; ++r) maxv[rt][r] = NEG_INF_F;

    const f32x4 ZERO4 = (f32x4){0.f, 0.f, 0.f, 0.f};
    const int ntFull   = nv >> 4;
    const int tailCols = nv & 15;
    const unsigned short* krow0 = &Ks[n * KSTRIDE + g * 8];

    // main loop: pairs of full 16-col tiles; no masking needed (all columns valid)
    int ct = 0;
    for (; ct + 1 < ntFull; ct += 2) {
        const unsigned short* ka = krow0 + ct * 16 * KSTRIDE;
        short8 kA0 = *(const short8*)(ka);
        short8 kA1 = *(const short8*)(ka + 32);
        short8 kB0 = *(const short8*)(ka + 16 * KSTRIDE);
        short8 kB1 = *(const short8*)(ka + 16 * KSTRIDE + 32);

        f32x4 accA[4], accB[4];
        #pragma unroll
        for (int rt = 0; rt < 4; ++rt) {
            accA[rt] = __builtin_amdgcn_mfma_f32_16x16x32_bf16(afrag[rt][0], kA0, ZERO4, 0, 0, 0);
            accB[rt] = __builtin_amdgcn_mfma_f32_16x16x32_bf16(afrag[rt][0], kB0, ZERO4, 0, 0, 0);
        }
        #pragma unroll
        for (int rt = 0; rt < 4; ++rt) {
            accA[rt] = __builtin_amdgcn_mfma_f32_16x16x32_bf16(afrag[rt][1], kA1, accA[rt], 0, 0, 0);
            accB[rt] = __builtin_amdgcn_mfma_f32_16x16x32_bf16(afrag[rt][1], kB1, accB[rt], 0, 0, 0);
        }
        // running max; nested fmax -> v_max3_f32
        #pragma unroll
        for (int rt = 0; rt < 4; ++rt)
            #pragma unroll
            for (int r = 0; r < 4; ++r)
                maxv[rt][r] = fmaxf(maxv[rt][r], fmaxf(accA[rt][r], accB[rt][r]));
    }

    // leftover single full tile
    if (ntFull & 1) {
        const unsigned short* ka = krow0 + ct * 16 * KSTRIDE;
        short8 k0 = *(const short8*)(ka);
        short8 k1 = *(const short8*)(ka + 32);
        f32x4 acc[4];
        #pragma unroll
        for (int rt = 0; rt < 4; ++rt)
            acc[rt] = __builtin_amdgcn_mfma_f32_16x16x32_bf16(afrag[rt][0], k0, ZERO4, 0, 0, 0);
        #pragma unroll
        for (int rt = 0; rt < 4; ++rt)
            acc[rt] = __builtin_amdgcn_mfma_f32_16x16x32_bf16(afrag[rt][1], k1, acc[rt], 0, 0, 0);
        #pragma unroll
        for (int rt = 0; rt < 4; ++rt)
            #pragma unroll
            for (int r = 0; r < 4; ++r)
                maxv[rt][r] = fmaxf(maxv[rt][r], acc[rt][r]);
        ct++;
    }

    // tail tile: pad lanes get NEG_INF via the MFMA C-operand bias (no per-element cndmask)
    if (tailCols) {
        float biasv = (n < tailCols) ? 0.0f : NEG_INF_F;
        f32x4 BIAS4 = (f32x4){biasv, biasv, biasv, biasv};
        const unsigned short* ka = krow0 + ct * 16 * KSTRIDE;
        short8 k0 = *(const short8*)(ka);
        short8 k1 = *(const short8*)(ka + 32);
        f32x4 acc[4];
        #pragma unroll
        for (int rt = 0; rt < 4; ++rt)
            acc[rt] = __builtin_amdgcn_mfma_f32_16x16x32_bf16(afrag[rt][0], k0, BIAS4, 0, 0, 0);
        #pragma unroll
        for (int rt = 0; rt < 4; ++rt)
            acc[rt] = __builtin_amdgcn_mfma_f32_16x16x32_bf16(afrag[rt][1], k1, acc[rt], 0, 0, 0);
        #pragma unroll
        for (int rt = 0; rt < 4; ++rt)
            #pragma unroll
            for (int r = 0; r < 4; ++r)
                maxv[rt][r] = fmaxf(maxv[rt][r], acc[rt][r]);
    }

    // Max across the 16 lanes (cols) of each quad group.
    #pragma unroll
    for (int rt = 0; rt < 4; ++rt)
        #pragma unroll
        for (int r = 0; r < 4; ++r) {
            float mv = maxv[rt][r];
            mv = fmaxf(mv, __shfl_xor(mv, 1, 16));
            mv = fmaxf(mv, __shfl_xor(mv, 2, 16));
            mv = fmaxf(mv, __shfl_xor(mv, 4, 16));
            mv = fmaxf(mv, __shfl_xor(mv, 8, 16));
            maxv[rt][r] = mv;
        }

    // qmask-weighted sum; count each row once (n==0 lanes). qmask read straight
    // from L2 (64KB, hot) - no LDS staging needed.
    float partial = 0.0f;
    if (n == 0) {
        const int* qm = qmask + b * PL;
        #pragma unroll
        for (int rt = 0; rt < 4; ++rt)
            #pragma unroll
            for (int r = 0; r < 4; ++r) {
                int row = qw0 + rt * 16 + g * 4 + r;
                partial += maxv[rt][r] * (float)qm[row];
            }
    }
    partial += __shfl_xor(partial, 16, 64);
    partial += __shfl_xor(partial, 32, 64);
    if (lane == 0) red[wave] = partial;
    __syncthreads();
    if (tid == 0) {
        float total = red[0] + red[1] + red[2] + red[3];
        scores[b * PB + c] = total * (1.0f / TEMP);
    }
}

// ---------------- finalize: log-softmax CE ----------------
__global__ void finalize_kernel(const float* __restrict__ scores,
                                const int*   __restrict__ labels,
                                float*       __restrict__ out) {
    const int r = threadIdx.x;   // 64 threads, one per row
    const float* row = scores + r * PB;
    float mx = NEG_INF_F;
    for (int j = 0; j < PB; ++j) mx = fmaxf(mx, row[j]);
    float se = 0.0f;
    for (int j = 0; j < PB; ++j) se += expf(row[j] - mx);
    float logp_diag = row[r] - mx - logf(se);
    float w = (float)labels[r];
    float wd = w * logp_diag;
    #pragma unroll
    for (int off = 32; off >= 1; off >>= 1) {
        wd += __shfl_xor(wd, off, 64);
        w  += __shfl_xor(w,  off, 64);
    }
    if (r == 0) out[0] = -wd / fmaxf(w, 1.0f);
}

extern "C" void kernel_launch(void* const* d_in, const int* in_sizes, int n_in,
                              void* d_out, int out_size, void* d_ws, size_t ws_size,
                              hipStream_t stream) {
    const float* Q      = (const float*)d_in[0];
    const float* K      = (const float*)d_in[1];
    const int*   labels = (const int*)d_in[2];
    const int*   qmask  = (const int*)d_in[3];
    const int*   kmask  = (const int*)d_in[4];
    float*       out    = (float*)d_out;

    // ws layout: [scores 16KB][Qb 2MB][Kcomp 2.25MB][nvK 256B]
    char* ws = (char*)d_ws;
    float*          scores = (float*)ws;
    unsigned short* Qb     = (unsigned short*)(ws + 16 * 1024);
    unsigned short* Kcomp  = (unsigned short*)(ws + 16 * 1024 + 2 * 1024 * 1024);
    int*            nvK    = (int*)(ws + 16 * 1024 + 2 * 1024 * 1024 + (size_t)PB * KSLAB * 2);

    prep_kernel<<<512, 256, 0, stream>>>(Q, K, kmask, Qb, Kcomp, nvK);

    dim3 grid(PB, PB);
    colbert_scores_mfma<<<grid, 256, 0, stream>>>(Qb, Kcomp, nvK, qmask, scores);
    finalize_kernel<<<1, 64, 0, stream>>>(scores, labels, out);
}